// Round 4
// baseline (241.106 us; speedup 1.0000x reference)
//
#include <hip/hip_runtime.h>

#define DIM  128
#define HID  32
#define KTOT 384          // 3*DIM
#define TPW  16           // edges per wave-tile

typedef __attribute__((ext_vector_type(8))) unsigned short u16x8;
typedef __attribute__((ext_vector_type(4))) unsigned short u16x4;
typedef __bf16 bf16x8 __attribute__((ext_vector_type(8)));
typedef __attribute__((ext_vector_type(4))) float f32x4;

static __device__ inline unsigned short f2bf(float f) {
    unsigned u = __float_as_uint(f);
    return (unsigned short)((u + 0x7fff + ((u >> 16) & 1)) >> 16);  // RNE
}

// ---------------------------------------------------------------------------
// Kernel 0 "prep0": blocks 0..31  -> wsum[r] = sum_d W[r][d] (1 row per wave)
//                   blocks 32..79 -> w1T[h][k] = bf16(w1[k][h])  (384x32)
// (einsum 'ed,ef->e' factorizes: bilinear[e] = (z_src.wsum)*(sum z_dst))
// ---------------------------------------------------------------------------
__global__ __launch_bounds__(256) void prep0_kernel(
    const float* __restrict__ W, const float* __restrict__ w1,
    float* __restrict__ wsum, unsigned short* __restrict__ w1T)
{
    const int b = blockIdx.x;
    const int tid = threadIdx.x;
    if (b < 32) {
        const int wv = tid >> 6, lane = tid & 63;
        const int r = b * 4 + wv;                 // 0..127
        float2 v = *(const float2*)(W + (size_t)r * DIM + lane * 2);
        float s = v.x + v.y;
        s += __shfl_xor(s, 1);  s += __shfl_xor(s, 2);  s += __shfl_xor(s, 4);
        s += __shfl_xor(s, 8);  s += __shfl_xor(s, 16); s += __shfl_xor(s, 32);
        if (lane == 0) wsum[r] = s;
    } else {
        const int idx = (b - 32) * 256 + tid;     // 0..12287 exact
        const int k = idx >> 5, h = idx & 31;
        w1T[(size_t)h * KTOT + k] = f2bf(w1[idx]);
    }
}

// ---------------------------------------------------------------------------
// Kernel 1: per-node, HALF-WAVE per node (32 lanes x float4 = 512B row, fully
// coalesced; no cross-iteration line reuse needed -> no L1 thrash).
//   zb16[n][:] = bf16(z[n][:]), s1[n] = z.wsum, s2[n] = sum z
// ---------------------------------------------------------------------------
__global__ __launch_bounds__(256) void node_precompute(
    const float* __restrict__ z, const float* __restrict__ wsum,
    unsigned short* __restrict__ zb16,
    float* __restrict__ s1, float* __restrict__ s2, int nNodes)
{
    const int tid = threadIdx.x;
    const int n = blockIdx.x * 8 + (tid >> 5);    // 8 nodes / 256-thread block
    const int l32 = tid & 31;
    if (n >= nNodes) return;                       // half-wave-uniform exit

    float4 v = *(const float4*)(z + (size_t)n * DIM + l32 * 4);
    float4 w = *(const float4*)(wsum + l32 * 4);

    float a1 = v.x * w.x + v.y * w.y + v.z * w.z + v.w * w.w;
    float a2 = v.x + v.y + v.z + v.w;

    u16x4 o;
    o[0] = f2bf(v.x); o[1] = f2bf(v.y); o[2] = f2bf(v.z); o[3] = f2bf(v.w);
    *(u16x4*)(zb16 + (size_t)n * DIM + l32 * 4) = o;

    // reduce within the 32-lane half-wave (xor<=16 stays in-half)
    a1 += __shfl_xor(a1, 1);  a1 += __shfl_xor(a1, 2);  a1 += __shfl_xor(a1, 4);
    a1 += __shfl_xor(a1, 8);  a1 += __shfl_xor(a1, 16);
    a2 += __shfl_xor(a2, 1);  a2 += __shfl_xor(a2, 2);  a2 += __shfl_xor(a2, 4);
    a2 += __shfl_xor(a2, 8);  a2 += __shfl_xor(a2, 16);
    if (l32 == 0) { s1[n] = a1; s2[n] = a2; }
}

// ---------------------------------------------------------------------------
// Edge kernel helpers
// ---------------------------------------------------------------------------
__device__ __forceinline__ void load_tile(
    int t, int nE, const int* __restrict__ ei,
    const float* __restrict__ s1, const float* __restrict__ s2,
    const unsigned short* __restrict__ zb16, int l15, int quad,
    u16x8 zs[4], u16x8 zd[4], float& bil)
{
    const int e = t * TPW + l15;
    int s_ = 0, d_ = 0;
    if (e < nE) { s_ = ei[e]; d_ = ei[nE + e]; }
    bil = s1[s_] * s2[d_];
    const unsigned short* zsp = zb16 + (size_t)s_ * DIM + quad * 8;
    const unsigned short* zdp = zb16 + (size_t)d_ * DIM + quad * 8;
#pragma unroll
    for (int k = 0; k < 4; k++) {
        zs[k] = *(const u16x8*)(zsp + k * 32);
        zd[k] = *(const u16x8*)(zdp + k * 32);
    }
}

__device__ __forceinline__ void compute_tile(
    const u16x8 zs[4], const u16x8 zd[4], float bil, int t,
    const bf16x8 B0[12], const bf16x8 B1[12],
    float b1a, float w2a, float b1b, float w2b, float cbias,
    int quad, int l15, int nE, float* __restrict__ out)
{
    f32x4 acc0 = {0.f, 0.f, 0.f, 0.f}, acc1 = {0.f, 0.f, 0.f, 0.f};
#pragma unroll
    for (int k = 0; k < 4; k++) {               // zs block (K 0..127)
        bf16x8 a = __builtin_bit_cast(bf16x8, zs[k]);
        acc0 = __builtin_amdgcn_mfma_f32_16x16x32_bf16(a, B0[k], acc0, 0, 0, 0);
        acc1 = __builtin_amdgcn_mfma_f32_16x16x32_bf16(a, B1[k], acc1, 0, 0, 0);
    }
#pragma unroll
    for (int k = 0; k < 4; k++) {               // zd block (K 128..255)
        bf16x8 a = __builtin_bit_cast(bf16x8, zd[k]);
        acc0 = __builtin_amdgcn_mfma_f32_16x16x32_bf16(a, B0[4 + k], acc0, 0, 0, 0);
        acc1 = __builtin_amdgcn_mfma_f32_16x16x32_bf16(a, B1[4 + k], acc1, 0, 0, 0);
    }
#pragma unroll
    for (int k = 0; k < 4; k++) {               // product block (K 256..383)
        const unsigned* su = (const unsigned*)&zs[k];
        const unsigned* du = (const unsigned*)&zd[k];
        u16x8 p;
        unsigned* pu = (unsigned*)&p;
#pragma unroll
        for (int j = 0; j < 4; j++) {           // 2 bf16 elems per iter
            unsigned a_ = su[j], b_ = du[j];
            float alo = __uint_as_float(a_ << 16);
            float ahi = __uint_as_float(a_ & 0xffff0000u);
            float blo = __uint_as_float(b_ << 16);
            float bhi = __uint_as_float(b_ & 0xffff0000u);
            unsigned plo = __float_as_uint(alo * blo) + 0x8000u;   // round-half-up
            unsigned phi = __float_as_uint(ahi * bhi) + 0x8000u;
            pu[j] = __builtin_amdgcn_perm(phi, plo, 0x07060302);   // hi16s packed
        }
        bf16x8 a = __builtin_bit_cast(bf16x8, p);
        acc0 = __builtin_amdgcn_mfma_f32_16x16x32_bf16(a, B0[8 + k], acc0, 0, 0, 0);
        acc1 = __builtin_amdgcn_mfma_f32_16x16x32_bf16(a, B1[8 + k], acc1, 0, 0, 0);
    }

    // epilogue: C/D col=l15 (h), row=quad*4+r (edge). Reduce over h.
    const int e0 = t * TPW;
#pragma unroll
    for (int r = 0; r < 4; r++) {
        float v = fmaxf(acc0[r] + b1a, 0.f) * w2a
                + fmaxf(acc1[r] + b1b, 0.f) * w2b;
        v += __shfl_xor(v, 1); v += __shfl_xor(v, 2);
        v += __shfl_xor(v, 4); v += __shfl_xor(v, 8);
        const int eL = quad * 4 + r;
        const float bilr = __shfl(bil, eL);     // bil lives on lane eL (per 16-group)
        if (l15 == r && (e0 + eL) < nE)
            out[e0 + eL] = v + bilr + cbias;
    }
}

// ---------------------------------------------------------------------------
// Kernel 2: edge kernel — wave-autonomous, zero LDS/barriers, software-
// pipelined register double-buffer (load tile t+1 before computing tile t).
// ---------------------------------------------------------------------------
__global__ __launch_bounds__(256, 4) void edge_kernel(
    const unsigned short* __restrict__ zb16, const int* __restrict__ ei,
    const float* __restrict__ s1, const float* __restrict__ s2,
    const unsigned short* __restrict__ w1T, const float* __restrict__ b1,
    const float* __restrict__ w2, const float* __restrict__ b2,
    const float* __restrict__ bias, float* __restrict__ out,
    int nE, int nTiles)
{
    const int lane = threadIdx.x & 63;
    const int wv   = threadIdx.x >> 6;
    const int l15  = lane & 15;
    const int quad = lane >> 4;

    int t = blockIdx.x * 4 + wv;
    const int nW = gridDim.x * 4;
    if (t >= nTiles) return;

    // B fragments: B[k][n], n=l15 (h), k=quad*8+j per 32-step
    bf16x8 B0[12], B1[12];
    {
        const unsigned short* b0p = w1T + (size_t)l15 * KTOT + quad * 8;
        const unsigned short* b1p = w1T + (size_t)(16 + l15) * KTOT + quad * 8;
#pragma unroll
        for (int s = 0; s < 12; s++) {
            B0[s] = __builtin_bit_cast(bf16x8, *(const u16x8*)(b0p + s * 32));
            B1[s] = __builtin_bit_cast(bf16x8, *(const u16x8*)(b1p + s * 32));
        }
    }
    const float b1a = b1[l15],      w2a = w2[l15];
    const float b1b = b1[16 + l15], w2b = w2[16 + l15];
    const float cbias = bias[0] + b2[0];

    u16x8 zsA[4], zdA[4], zsB[4], zdB[4];
    float bilA, bilB;

    load_tile(t, nE, ei, s1, s2, zb16, l15, quad, zsA, zdA, bilA);
    while (true) {
        const int t1 = t + nW;
        if (t1 < nTiles)
            load_tile(t1, nE, ei, s1, s2, zb16, l15, quad, zsB, zdB, bilB);
        compute_tile(zsA, zdA, bilA, t, B0, B1, b1a, w2a, b1b, w2b, cbias,
                     quad, l15, nE, out);
        if (t1 >= nTiles) break;

        const int t2 = t1 + nW;
        if (t2 < nTiles)
            load_tile(t2, nE, ei, s1, s2, zb16, l15, quad, zsA, zdA, bilA);
        compute_tile(zsB, zdB, bilB, t1, B0, B1, b1a, w2a, b1b, w2b, cbias,
                     quad, l15, nE, out);
        if (t2 >= nTiles) break;
        t = t2;
    }
}

// ---------------------------------------------------------------------------
// Workspace: zb16 ushort[nNodes*128] | w1T ushort[32*384] | s1 | s2 | wsum[128]
// ~26.5 MB for nNodes=100000.
// ---------------------------------------------------------------------------
extern "C" void kernel_launch(void* const* d_in, const int* in_sizes, int n_in,
                              void* d_out, int out_size, void* d_ws, size_t ws_size,
                              hipStream_t stream)
{
    const float* z    = (const float*)d_in[0];
    const int*   ei   = (const int*)d_in[1];
    const float* W    = (const float*)d_in[2];
    const float* bias = (const float*)d_in[3];
    const float* w1   = (const float*)d_in[4];
    const float* b1   = (const float*)d_in[5];
    const float* w2   = (const float*)d_in[6];
    const float* b2   = (const float*)d_in[7];
    float* out = (float*)d_out;

    const int nNodes = in_sizes[0] / DIM;
    const int nE = out_size;

    unsigned short* zb16 = (unsigned short*)d_ws;
    unsigned short* w1T  = zb16 + (size_t)nNodes * DIM;
    float* s1   = (float*)(w1T + (size_t)HID * KTOT);
    float* s2   = s1 + nNodes;
    float* wsum = s2 + nNodes;

    prep0_kernel<<<80, 256, 0, stream>>>(W, w1, wsum, w1T);

    int preBlocks = (nNodes + 7) / 8;
    node_precompute<<<preBlocks, 256, 0, stream>>>(z, wsum, zb16, s1, s2, nNodes);

    const int nTiles = (nE + TPW - 1) / TPW;
    int grid = 1024;                      // 4 blocks/CU, 16 waves/CU @ 4 waves/EU
    if (grid * 4 > nTiles) grid = (nTiles + 3) / 4;
    edge_kernel<<<grid, 256, 0, stream>>>(zb16, ei, s1, s2, w1T,
                                          b1, w2, b2, bias, out, nE, nTiles);
}

// Round 5
// 157.899 us; speedup vs baseline: 1.5270x; 1.5270x over previous
//
#include <hip/hip_runtime.h>

#define DIM  128
#define HID  32
#define KTOT 384          // 3*DIM
#define TPW  16           // edges per wave-tile

typedef __attribute__((ext_vector_type(8))) unsigned short u16x8;
typedef __attribute__((ext_vector_type(4))) unsigned short u16x4;
typedef __bf16 bf16x8 __attribute__((ext_vector_type(8)));
typedef __attribute__((ext_vector_type(4))) float f32x4;

static __device__ inline unsigned short f2bf(float f) {
    unsigned u = __float_as_uint(f);
    return (unsigned short)((u + 0x7fff + ((u >> 16) & 1)) >> 16);  // RNE
}

// ---------------------------------------------------------------------------
// Kernel 0 "prep0": blocks 0..31  -> wsum[r] = sum_d W[r][d] (1 row per wave)
//                   blocks 32..79 -> w1T[h][k] = bf16(w1[k][h])  (384x32)
// (einsum 'ed,ef->e' factorizes: bilinear[e] = (z_src.wsum)*(sum z_dst))
// ---------------------------------------------------------------------------
__global__ __launch_bounds__(256) void prep0_kernel(
    const float* __restrict__ W, const float* __restrict__ w1,
    float* __restrict__ wsum, unsigned short* __restrict__ w1T)
{
    const int b = blockIdx.x;
    const int tid = threadIdx.x;
    if (b < 32) {
        const int wv = tid >> 6, lane = tid & 63;
        const int r = b * 4 + wv;                 // 0..127
        float2 v = *(const float2*)(W + (size_t)r * DIM + lane * 2);
        float s = v.x + v.y;
        s += __shfl_xor(s, 1);  s += __shfl_xor(s, 2);  s += __shfl_xor(s, 4);
        s += __shfl_xor(s, 8);  s += __shfl_xor(s, 16); s += __shfl_xor(s, 32);
        if (lane == 0) wsum[r] = s;
    } else {
        const int idx = (b - 32) * 256 + tid;     // 0..12287 exact
        const int k = idx >> 5, h = idx & 31;
        w1T[(size_t)h * KTOT + k] = f2bf(w1[idx]);
    }
}

// ---------------------------------------------------------------------------
// Kernel 1: per-node, HALF-WAVE per node (32 lanes x float4 = 512B row, fully
// coalesced).  zb16[n][:] = bf16(z[n][:]), s1[n] = z.wsum, s2[n] = sum z
// ---------------------------------------------------------------------------
__global__ __launch_bounds__(256) void node_precompute(
    const float* __restrict__ z, const float* __restrict__ wsum,
    unsigned short* __restrict__ zb16,
    float* __restrict__ s1, float* __restrict__ s2, int nNodes)
{
    const int tid = threadIdx.x;
    const int n = blockIdx.x * 8 + (tid >> 5);    // 8 nodes / 256-thread block
    const int l32 = tid & 31;
    if (n >= nNodes) return;                       // half-wave-uniform exit

    float4 v = *(const float4*)(z + (size_t)n * DIM + l32 * 4);
    float4 w = *(const float4*)(wsum + l32 * 4);

    float a1 = v.x * w.x + v.y * w.y + v.z * w.z + v.w * w.w;
    float a2 = v.x + v.y + v.z + v.w;

    u16x4 o;
    o[0] = f2bf(v.x); o[1] = f2bf(v.y); o[2] = f2bf(v.z); o[3] = f2bf(v.w);
    *(u16x4*)(zb16 + (size_t)n * DIM + l32 * 4) = o;

    a1 += __shfl_xor(a1, 1);  a1 += __shfl_xor(a1, 2);  a1 += __shfl_xor(a1, 4);
    a1 += __shfl_xor(a1, 8);  a1 += __shfl_xor(a1, 16);
    a2 += __shfl_xor(a2, 1);  a2 += __shfl_xor(a2, 2);  a2 += __shfl_xor(a2, 4);
    a2 += __shfl_xor(a2, 8);  a2 += __shfl_xor(a2, 16);
    if (l32 == 0) { s1[n] = a1; s2[n] = a2; }
}

// ---------------------------------------------------------------------------
// Edge kernel helpers
// ---------------------------------------------------------------------------
__device__ __forceinline__ void load_tile(
    int t, int nE, const int* __restrict__ ei,
    const float* __restrict__ s1, const float* __restrict__ s2,
    const unsigned short* __restrict__ zb16, int l15, int quad,
    u16x8 zs[4], u16x8 zd[4], float& bil)
{
    const int e = t * TPW + l15;
    int s_ = 0, d_ = 0;
    if (e < nE) { s_ = ei[e]; d_ = ei[nE + e]; }
    bil = s1[s_] * s2[d_];
    const unsigned short* zsp = zb16 + (size_t)s_ * DIM + quad * 8;
    const unsigned short* zdp = zb16 + (size_t)d_ * DIM + quad * 8;
#pragma unroll
    for (int k = 0; k < 4; k++) {
        zs[k] = *(const u16x8*)(zsp + k * 32);
        zd[k] = *(const u16x8*)(zdp + k * 32);
    }
}

__device__ __forceinline__ void compute_tile(
    const u16x8 zs[4], const u16x8 zd[4], float bil, int t,
    const bf16x8 B0[12], const bf16x8 B1[12],
    float b1a, float w2a, float b1b, float w2b, float cbias,
    int quad, int l15, int nE, float* __restrict__ out)
{
    f32x4 acc0 = {0.f, 0.f, 0.f, 0.f}, acc1 = {0.f, 0.f, 0.f, 0.f};
#pragma unroll
    for (int k = 0; k < 4; k++) {               // zs block (K 0..127)
        bf16x8 a = __builtin_bit_cast(bf16x8, zs[k]);
        acc0 = __builtin_amdgcn_mfma_f32_16x16x32_bf16(a, B0[k], acc0, 0, 0, 0);
        acc1 = __builtin_amdgcn_mfma_f32_16x16x32_bf16(a, B1[k], acc1, 0, 0, 0);
    }
#pragma unroll
    for (int k = 0; k < 4; k++) {               // zd block (K 128..255)
        bf16x8 a = __builtin_bit_cast(bf16x8, zd[k]);
        acc0 = __builtin_amdgcn_mfma_f32_16x16x32_bf16(a, B0[4 + k], acc0, 0, 0, 0);
        acc1 = __builtin_amdgcn_mfma_f32_16x16x32_bf16(a, B1[4 + k], acc1, 0, 0, 0);
    }
#pragma unroll
    for (int k = 0; k < 4; k++) {               // product block (K 256..383)
        const unsigned* su = (const unsigned*)&zs[k];
        const unsigned* du = (const unsigned*)&zd[k];
        u16x8 p;
        unsigned* pu = (unsigned*)&p;
#pragma unroll
        for (int j = 0; j < 4; j++) {           // 2 bf16 elems per iter
            unsigned a_ = su[j], b_ = du[j];
            float alo = __uint_as_float(a_ << 16);
            float ahi = __uint_as_float(a_ & 0xffff0000u);
            float blo = __uint_as_float(b_ << 16);
            float bhi = __uint_as_float(b_ & 0xffff0000u);
            unsigned plo = __float_as_uint(alo * blo) + 0x8000u;   // round-half-up
            unsigned phi = __float_as_uint(ahi * bhi) + 0x8000u;
            pu[j] = __builtin_amdgcn_perm(phi, plo, 0x07060302);   // hi16s packed
        }
        bf16x8 a = __builtin_bit_cast(bf16x8, p);
        acc0 = __builtin_amdgcn_mfma_f32_16x16x32_bf16(a, B0[8 + k], acc0, 0, 0, 0);
        acc1 = __builtin_amdgcn_mfma_f32_16x16x32_bf16(a, B1[8 + k], acc1, 0, 0, 0);
    }

    // epilogue: C/D col=l15 (h), row=quad*4+r (edge). Reduce over h.
    const int e0 = t * TPW;
#pragma unroll
    for (int r = 0; r < 4; r++) {
        float v = fmaxf(acc0[r] + b1a, 0.f) * w2a
                + fmaxf(acc1[r] + b1b, 0.f) * w2b;
        v += __shfl_xor(v, 1); v += __shfl_xor(v, 2);
        v += __shfl_xor(v, 4); v += __shfl_xor(v, 8);
        const int eL = quad * 4 + r;
        const float bilr = __shfl(bil, eL);     // bil lives on lane eL
        if (l15 == r && (e0 + eL) < nE)
            out[e0 + eL] = v + bilr + cbias;
    }
}

// ---------------------------------------------------------------------------
// Kernel 2: edge kernel — wave-autonomous, zero LDS/barriers, register
// double-buffered across tiles. __launch_bounds__(256,2): VGPR cap 256 so the
// ~200 live regs (B=96, 2x A-buffers=64, acc, addr) FIT — R4's (256,4) cap of
// 64 caused catastrophic scratch spills (WRITE_SIZE 2->77MB). 2 waves/EU with
// 2 tiles of gathers in flight each = 2x the in-flight loads of R3 (MLP-bound).
// ---------------------------------------------------------------------------
__global__ __launch_bounds__(256, 2) void edge_kernel(
    const unsigned short* __restrict__ zb16, const int* __restrict__ ei,
    const float* __restrict__ s1, const float* __restrict__ s2,
    const unsigned short* __restrict__ w1T, const float* __restrict__ b1,
    const float* __restrict__ w2, const float* __restrict__ b2,
    const float* __restrict__ bias, float* __restrict__ out,
    int nE, int nTiles)
{
    const int lane = threadIdx.x & 63;
    const int wv   = threadIdx.x >> 6;
    const int l15  = lane & 15;
    const int quad = lane >> 4;

    int t = blockIdx.x * 4 + wv;
    const int nW = gridDim.x * 4;
    if (t >= nTiles) return;

    // B fragments: B[k][n], n=l15 (h), k=quad*8+j per 32-step
    bf16x8 B0[12], B1[12];
    {
        const unsigned short* b0p = w1T + (size_t)l15 * KTOT + quad * 8;
        const unsigned short* b1p = w1T + (size_t)(16 + l15) * KTOT + quad * 8;
#pragma unroll
        for (int s = 0; s < 12; s++) {
            B0[s] = __builtin_bit_cast(bf16x8, *(const u16x8*)(b0p + s * 32));
            B1[s] = __builtin_bit_cast(bf16x8, *(const u16x8*)(b1p + s * 32));
        }
    }
    const float b1a = b1[l15],      w2a = w2[l15];
    const float b1b = b1[16 + l15], w2b = w2[16 + l15];
    const float cbias = bias[0] + b2[0];

    u16x8 zsA[4], zdA[4], zsB[4], zdB[4];
    float bilA, bilB;

    load_tile(t, nE, ei, s1, s2, zb16, l15, quad, zsA, zdA, bilA);
    while (true) {
        const int t1 = t + nW;
        if (t1 < nTiles)
            load_tile(t1, nE, ei, s1, s2, zb16, l15, quad, zsB, zdB, bilB);
        compute_tile(zsA, zdA, bilA, t, B0, B1, b1a, w2a, b1b, w2b, cbias,
                     quad, l15, nE, out);
        if (t1 >= nTiles) break;

        const int t2 = t1 + nW;
        if (t2 < nTiles)
            load_tile(t2, nE, ei, s1, s2, zb16, l15, quad, zsA, zdA, bilA);
        compute_tile(zsB, zdB, bilB, t1, B0, B1, b1a, w2a, b1b, w2b, cbias,
                     quad, l15, nE, out);
        if (t2 >= nTiles) break;
        t = t2;
    }
}

// ---------------------------------------------------------------------------
// Workspace: zb16 ushort[nNodes*128] | w1T ushort[32*384] | s1 | s2 | wsum[128]
// ~26.5 MB for nNodes=100000.
// ---------------------------------------------------------------------------
extern "C" void kernel_launch(void* const* d_in, const int* in_sizes, int n_in,
                              void* d_out, int out_size, void* d_ws, size_t ws_size,
                              hipStream_t stream)
{
    const float* z    = (const float*)d_in[0];
    const int*   ei   = (const int*)d_in[1];
    const float* W    = (const float*)d_in[2];
    const float* bias = (const float*)d_in[3];
    const float* w1   = (const float*)d_in[4];
    const float* b1   = (const float*)d_in[5];
    const float* w2   = (const float*)d_in[6];
    const float* b2   = (const float*)d_in[7];
    float* out = (float*)d_out;

    const int nNodes = in_sizes[0] / DIM;
    const int nE = out_size;

    unsigned short* zb16 = (unsigned short*)d_ws;
    unsigned short* w1T  = zb16 + (size_t)nNodes * DIM;
    float* s1   = (float*)(w1T + (size_t)HID * KTOT);
    float* s2   = s1 + nNodes;
    float* wsum = s2 + nNodes;

    prep0_kernel<<<80, 256, 0, stream>>>(W, w1, wsum, w1T);

    int preBlocks = (nNodes + 7) / 8;
    node_precompute<<<preBlocks, 256, 0, stream>>>(z, wsum, zb16, s1, s2, nNodes);

    const int nTiles = (nE + TPW - 1) / TPW;
    int grid = 1024;                      // HW caps residency by regs; rest queue
    if (grid * 4 > nTiles) grid = (nTiles + 3) / 4;
    edge_kernel<<<grid, 256, 0, stream>>>(zb16, ei, s1, s2, w1T,
                                          b1, w2, b2, bias, out, nE, nTiles);
}

// Round 6
// 151.651 us; speedup vs baseline: 1.5899x; 1.0412x over previous
//
#include <hip/hip_runtime.h>

#define DIM  128
#define HID  32
#define KTOT 384          // 3*DIM
#define TPW  16           // edges per wave-tile

typedef __attribute__((ext_vector_type(8))) unsigned short u16x8;
typedef __attribute__((ext_vector_type(4))) unsigned short u16x4;
typedef __bf16 bf16x8 __attribute__((ext_vector_type(8)));
typedef __attribute__((ext_vector_type(4))) float f32x4;

static __device__ inline unsigned short f2bf(float f) {
    unsigned u = __float_as_uint(f);
    return (unsigned short)((u + 0x7fff + ((u >> 16) & 1)) >> 16);  // RNE
}

// ---------------------------------------------------------------------------
// prep kernel (ONE launch, all parts independent):
//  blocks [0, nConv)          : flat coalesced f32->bf16 convert of z (8 elems/thread)
//  blocks [nConv, nConv+32)   : wsumb[r] = bf16(sum_d W[r][d])   (bilinear factor;
//                               einsum 'ed,ef->e' = (z_src.wsum)*(sum z_dst))
//  blocks [nConv+32, +48)     : w1T[h][k] = bf16(w1[k][h])  (384x32 transpose)
// ---------------------------------------------------------------------------
__global__ __launch_bounds__(256) void prep_kernel(
    const float* __restrict__ z, const float* __restrict__ W,
    const float* __restrict__ w1,
    unsigned short* __restrict__ zb16, unsigned short* __restrict__ w1T,
    unsigned short* __restrict__ wsumb, int nElems, int nConv)
{
    const int b = blockIdx.x;
    const int tid = threadIdx.x;
    if (b < nConv) {
        const size_t base = (size_t)b * 2048 + (size_t)tid * 8;
        if (base + 8 <= (size_t)nElems) {
            float4 v0 = *(const float4*)(z + base);
            float4 v1 = *(const float4*)(z + base + 4);
            u16x8 o;
            o[0] = f2bf(v0.x); o[1] = f2bf(v0.y); o[2] = f2bf(v0.z); o[3] = f2bf(v0.w);
            o[4] = f2bf(v1.x); o[5] = f2bf(v1.y); o[6] = f2bf(v1.z); o[7] = f2bf(v1.w);
            *(u16x8*)(zb16 + base) = o;
        } else {
            for (size_t i = base; i < (size_t)nElems; i++) zb16[i] = f2bf(z[i]);
        }
    } else if (b < nConv + 32) {
        const int wv = tid >> 6, lane = tid & 63;
        const int r = (b - nConv) * 4 + wv;       // 0..127
        float2 v = *(const float2*)(W + (size_t)r * DIM + lane * 2);
        float s = v.x + v.y;
        s += __shfl_xor(s, 1);  s += __shfl_xor(s, 2);  s += __shfl_xor(s, 4);
        s += __shfl_xor(s, 8);  s += __shfl_xor(s, 16); s += __shfl_xor(s, 32);
        if (lane == 0) wsumb[r] = f2bf(s);
    } else {
        const int idx = (b - nConv - 32) * 256 + tid;   // 0..12287 exact
        const int k = idx >> 5, h = idx & 31;
        w1T[(size_t)h * KTOT + k] = f2bf(w1[idx]);
    }
}

// ---------------------------------------------------------------------------
// Edge kernel — wave-autonomous, zero LDS/barriers, single-buffered (R5 dbuf
// was neutral: limiter is random-line service rate, not wave MLP).
// acc0/acc1: MLP hidden (h 0..15 / 16..31). acc2: augmented-B bilinear trick —
//  B2 col0 = wsum over K 0..127  -> acc2 col0 = s1 = z_src . wsum
//  B2 col1 = ones over K 128..255-> acc2 col1 = s2 = sum z_dst
//  bilinear = s1*s2 via one shfl_xor. No s1/s2 arrays, no per-edge scalar gathers.
// ---------------------------------------------------------------------------
__global__ __launch_bounds__(256, 2) void edge_kernel(
    const unsigned short* __restrict__ zb16, const int* __restrict__ ei,
    const unsigned short* __restrict__ w1T, const unsigned short* __restrict__ wsumb,
    const float* __restrict__ b1, const float* __restrict__ w2,
    const float* __restrict__ b2, const float* __restrict__ bias,
    float* __restrict__ out, int nE, int nTiles)
{
    const int lane = threadIdx.x & 63;
    const int wv   = threadIdx.x >> 6;
    const int l15  = lane & 15;
    const int quad = lane >> 4;

    int t = blockIdx.x * 4 + wv;
    const int nW = gridDim.x * 4;
    if (t >= nTiles) return;

    // B fragments: B[k][n], n=l15 (h), k=quad*8+j per 32-step
    bf16x8 B0[12], B1[12], B2[8];
    {
        const unsigned short* b0p = w1T + (size_t)l15 * KTOT + quad * 8;
        const unsigned short* b1p = w1T + (size_t)(16 + l15) * KTOT + quad * 8;
#pragma unroll
        for (int s = 0; s < 12; s++) {
            B0[s] = __builtin_bit_cast(bf16x8, *(const u16x8*)(b0p + s * 32));
            B1[s] = __builtin_bit_cast(bf16x8, *(const u16x8*)(b1p + s * 32));
        }
        u16x8 zero8; unsigned short* zp = (unsigned short*)&zero8;
#pragma unroll
        for (int j = 0; j < 8; j++) zp[j] = 0;
        u16x8 one8; unsigned short* op = (unsigned short*)&one8;
#pragma unroll
        for (int j = 0; j < 8; j++) op[j] = 0x3F80;   // bf16 1.0
#pragma unroll
        for (int s = 0; s < 8; s++) {
            u16x8 w = *(const u16x8*)(wsumb + (s & 3) * 32 + quad * 8);
            u16x8 sel = (l15 == 0 && s < 4) ? w : ((l15 == 1 && s >= 4) ? one8 : zero8);
            B2[s] = __builtin_bit_cast(bf16x8, sel);
        }
    }
    const float b1a = b1[l15],      w2a = w2[l15];
    const float b1b = b1[16 + l15], w2b = w2[16 + l15];
    const float cbias = bias[0] + b2[0];

    for (; t < nTiles; t += nW) {
        const int e = t * TPW + l15;
        int s_ = 0, d_ = 0;
        if (e < nE) { s_ = ei[e]; d_ = ei[nE + e]; }

        const unsigned short* zsp = zb16 + (size_t)s_ * DIM + quad * 8;
        const unsigned short* zdp = zb16 + (size_t)d_ * DIM + quad * 8;
        u16x8 zs[4], zd[4];
#pragma unroll
        for (int k = 0; k < 4; k++) {
            zs[k] = *(const u16x8*)(zsp + k * 32);
            zd[k] = *(const u16x8*)(zdp + k * 32);
        }

        f32x4 acc0 = {0.f, 0.f, 0.f, 0.f};
        f32x4 acc1 = {0.f, 0.f, 0.f, 0.f};
        f32x4 acc2 = {0.f, 0.f, 0.f, 0.f};
#pragma unroll
        for (int k = 0; k < 4; k++) {           // zs block (K 0..127)
            bf16x8 a = __builtin_bit_cast(bf16x8, zs[k]);
            acc0 = __builtin_amdgcn_mfma_f32_16x16x32_bf16(a, B0[k], acc0, 0, 0, 0);
            acc1 = __builtin_amdgcn_mfma_f32_16x16x32_bf16(a, B1[k], acc1, 0, 0, 0);
            acc2 = __builtin_amdgcn_mfma_f32_16x16x32_bf16(a, B2[k], acc2, 0, 0, 0);
        }
#pragma unroll
        for (int k = 0; k < 4; k++) {           // zd block (K 128..255)
            bf16x8 a = __builtin_bit_cast(bf16x8, zd[k]);
            acc0 = __builtin_amdgcn_mfma_f32_16x16x32_bf16(a, B0[4 + k], acc0, 0, 0, 0);
            acc1 = __builtin_amdgcn_mfma_f32_16x16x32_bf16(a, B1[4 + k], acc1, 0, 0, 0);
            acc2 = __builtin_amdgcn_mfma_f32_16x16x32_bf16(a, B2[4 + k], acc2, 0, 0, 0);
        }
#pragma unroll
        for (int k = 0; k < 4; k++) {           // product block (K 256..383)
            const unsigned* su = (const unsigned*)&zs[k];
            const unsigned* du = (const unsigned*)&zd[k];
            u16x8 p; unsigned* pu = (unsigned*)&p;
#pragma unroll
            for (int j = 0; j < 4; j++) {       // 2 bf16 elems per iter
                unsigned a_ = su[j], b_ = du[j];
                float alo = __uint_as_float(a_ << 16);
                float ahi = __uint_as_float(a_ & 0xffff0000u);
                float blo = __uint_as_float(b_ << 16);
                float bhi = __uint_as_float(b_ & 0xffff0000u);
                unsigned plo = __float_as_uint(alo * blo) + 0x8000u;
                unsigned phi = __float_as_uint(ahi * bhi) + 0x8000u;
                pu[j] = __builtin_amdgcn_perm(phi, plo, 0x07060302);
            }
            bf16x8 a = __builtin_bit_cast(bf16x8, p);
            acc0 = __builtin_amdgcn_mfma_f32_16x16x32_bf16(a, B0[8 + k], acc0, 0, 0, 0);
            acc1 = __builtin_amdgcn_mfma_f32_16x16x32_bf16(a, B1[8 + k], acc1, 0, 0, 0);
        }

        // epilogue: C/D col=l15, row=quad*4+r. Reduce MLP over h; bilinear from acc2.
        const int e0 = t * TPW;
#pragma unroll
        for (int r = 0; r < 4; r++) {
            float v = fmaxf(acc0[r] + b1a, 0.f) * w2a
                    + fmaxf(acc1[r] + b1b, 0.f) * w2b;
            v += __shfl_xor(v, 1); v += __shfl_xor(v, 2);
            v += __shfl_xor(v, 4); v += __shfl_xor(v, 8);
            float bil_r = acc2[r] * __shfl_xor(acc2[r], 1);  // s1*s2 (valid l15 0,1)
            float bilr  = __shfl(bil_r, lane & 48);          // l15=0 lane of this quad
            if (l15 == r && (e0 + quad * 4 + r) < nE)
                out[e0 + quad * 4 + r] = v + bilr + cbias;
        }
    }
}

// ---------------------------------------------------------------------------
// Workspace: zb16 ushort[nNodes*128] | w1T ushort[32*384] | wsumb ushort[128]
// ~25.7 MB for nNodes=100000.
// ---------------------------------------------------------------------------
extern "C" void kernel_launch(void* const* d_in, const int* in_sizes, int n_in,
                              void* d_out, int out_size, void* d_ws, size_t ws_size,
                              hipStream_t stream)
{
    const float* z    = (const float*)d_in[0];
    const int*   ei   = (const int*)d_in[1];
    const float* W    = (const float*)d_in[2];
    const float* bias = (const float*)d_in[3];
    const float* w1   = (const float*)d_in[4];
    const float* b1   = (const float*)d_in[5];
    const float* w2   = (const float*)d_in[6];
    const float* b2   = (const float*)d_in[7];
    float* out = (float*)d_out;

    const int nElems = in_sizes[0];           // nNodes*128
    const int nNodes = nElems / DIM;
    const int nE = out_size;

    unsigned short* zb16  = (unsigned short*)d_ws;
    unsigned short* w1T   = zb16 + (size_t)nNodes * DIM;
    unsigned short* wsumb = w1T + (size_t)HID * KTOT;

    const int nConv = (nElems + 2047) / 2048;
    prep_kernel<<<nConv + 32 + 48, 256, 0, stream>>>(z, W, w1, zb16, w1T, wsumb,
                                                     nElems, nConv);

    const int nTiles = (nE + TPW - 1) / TPW;
    int grid = 1024;
    if (grid * 4 > nTiles) grid = (nTiles + 3) / 4;
    edge_kernel<<<grid, 256, 0, stream>>>(zb16, ei, w1T, wsumb,
                                          b1, w2, b2, bias, out, nE, nTiles);
}

// Round 7
// 148.894 us; speedup vs baseline: 1.6193x; 1.0185x over previous
//
#include <hip/hip_runtime.h>

#define DIM  128
#define HID  32
#define KTOT 384          // 3*DIM
#define TPW  16           // edges per wave-tile

typedef __attribute__((ext_vector_type(4))) float f32x4;
typedef __attribute__((ext_vector_type(2))) float f32x2;

// fp8 e4m3 (OCP on gfx950) pack/unpack via HW converts
static __device__ __forceinline__ unsigned pk4_fp8(float a, float b, float c, float d) {
    unsigned r = __builtin_amdgcn_cvt_pk_fp8_f32(a, b, 0u, false);
    return __builtin_amdgcn_cvt_pk_fp8_f32(c, d, r, true);
}

// elementwise product of two 8-byte fp8 vectors, result fp8
static __device__ __forceinline__ long prod_fp8(long a, long b) {
    unsigned alo = (unsigned)(unsigned long)a, ahi = (unsigned)((unsigned long)a >> 32);
    unsigned blo = (unsigned)(unsigned long)b, bhi = (unsigned)((unsigned long)b >> 32);
    f32x2 a0 = __builtin_amdgcn_cvt_pk_f32_fp8(alo, false);
    f32x2 a1 = __builtin_amdgcn_cvt_pk_f32_fp8(alo, true);
    f32x2 a2 = __builtin_amdgcn_cvt_pk_f32_fp8(ahi, false);
    f32x2 a3 = __builtin_amdgcn_cvt_pk_f32_fp8(ahi, true);
    f32x2 b0 = __builtin_amdgcn_cvt_pk_f32_fp8(blo, false);
    f32x2 b1 = __builtin_amdgcn_cvt_pk_f32_fp8(blo, true);
    f32x2 b2 = __builtin_amdgcn_cvt_pk_f32_fp8(bhi, false);
    f32x2 b3 = __builtin_amdgcn_cvt_pk_f32_fp8(bhi, true);
    f32x2 p0 = a0 * b0, p1 = a1 * b1, p2 = a2 * b2, p3 = a3 * b3;
    unsigned plo = __builtin_amdgcn_cvt_pk_fp8_f32(p0.x, p0.y, 0u, false);
    plo = __builtin_amdgcn_cvt_pk_fp8_f32(p1.x, p1.y, plo, true);
    unsigned phi = __builtin_amdgcn_cvt_pk_fp8_f32(p2.x, p2.y, 0u, false);
    phi = __builtin_amdgcn_cvt_pk_fp8_f32(p3.x, p3.y, phi, true);
    return (long)(((unsigned long)phi << 32) | (unsigned long)plo);
}

// ---------------------------------------------------------------------------
// Kernel 0: wsum[r] = sum_d W[r][d], f32. (einsum 'ed,ef->e' factorizes:
// bilinear[e] = (z_src . wsum) * (sum_f z_dst[f]) = s1[src]*s2[dst])
// ---------------------------------------------------------------------------
__global__ void wsum_kernel(const float* __restrict__ W, float* __restrict__ wsum)
{
    int k = threadIdx.x;                 // 128 threads, one W row each
    const float4* row = (const float4*)(W + (size_t)k * DIM);
    float s = 0.f;
#pragma unroll
    for (int i = 0; i < DIM / 4; i++) {
        float4 v = row[i];
        s += v.x + v.y + v.z + v.w;
    }
    wsum[k] = s;
}

// ---------------------------------------------------------------------------
// Kernel 1 prep: blocks [0,nNodeBlk): half-wave per node —
//   zb8[n][:] = fp8(z[n][:]), s1[n] = z.wsum (f32), s2[n] = sum z (f32)
// blocks [nNodeBlk, +48): w1T8[h][k] = fp8(w1[k][h])  (384x32 transpose)
// ---------------------------------------------------------------------------
__global__ __launch_bounds__(256) void prep_kernel(
    const float* __restrict__ z, const float* __restrict__ w1,
    const float* __restrict__ wsum,
    unsigned char* __restrict__ zb8, unsigned char* __restrict__ w1T8,
    float* __restrict__ s1, float* __restrict__ s2,
    int nNodes, int nNodeBlk)
{
    const int b = blockIdx.x;
    const int tid = threadIdx.x;
    if (b < nNodeBlk) {
        const int n = b * 8 + (tid >> 5);
        const int l32 = tid & 31;
        if (n >= nNodes) return;                   // half-wave-uniform exit

        float4 v = *(const float4*)(z + (size_t)n * DIM + l32 * 4);
        float4 w = *(const float4*)(wsum + l32 * 4);

        float a1 = v.x * w.x + v.y * w.y + v.z * w.z + v.w * w.w;
        float a2 = v.x + v.y + v.z + v.w;

        *(unsigned*)(zb8 + (size_t)n * DIM + l32 * 4) = pk4_fp8(v.x, v.y, v.z, v.w);

        a1 += __shfl_xor(a1, 1);  a1 += __shfl_xor(a1, 2);  a1 += __shfl_xor(a1, 4);
        a1 += __shfl_xor(a1, 8);  a1 += __shfl_xor(a1, 16);
        a2 += __shfl_xor(a2, 1);  a2 += __shfl_xor(a2, 2);  a2 += __shfl_xor(a2, 4);
        a2 += __shfl_xor(a2, 8);  a2 += __shfl_xor(a2, 16);
        if (l32 == 0) { s1[n] = a1; s2[n] = a2; }
    } else {
        const int idx = (b - nNodeBlk) * 256 + tid;    // 0..12287 exact (48 blocks)
        const int k = idx >> 5, h = idx & 31;
        unsigned r = __builtin_amdgcn_cvt_pk_fp8_f32(w1[idx], 0.f, 0u, false);
        w1T8[(size_t)h * KTOT + k] = (unsigned char)(r & 0xff);
    }
}

// ---------------------------------------------------------------------------
// Kernel 2: edge kernel — wave-autonomous, zero LDS/barriers, fp8 gathers.
// Each fp8 row is 128B = ONE aligned L2 line (bf16 was 2) -> 2 lines/edge.
// MLP hidden = [zs | zd | zs*zd](fp8) @ w1(fp8) via mfma_f32_16x16x32_fp8_fp8;
// bilinear = s1[src]*s2[dst] in f32 (L2-resident 400KB arrays) for accuracy.
// A/B share the same lane->k mapping so the contraction is permutation-safe;
// C/D layout (col=l15, row=quad*4+r) is dtype-independent (m121/m127).
// ---------------------------------------------------------------------------
__global__ __launch_bounds__(256, 2) void edge_kernel(
    const unsigned char* __restrict__ zb8, const int* __restrict__ ei,
    const float* __restrict__ s1, const float* __restrict__ s2,
    const unsigned char* __restrict__ w1T8, const float* __restrict__ b1,
    const float* __restrict__ w2, const float* __restrict__ b2,
    const float* __restrict__ bias, float* __restrict__ out,
    int nE, int nTiles)
{
    const int lane = threadIdx.x & 63;
    const int wv   = threadIdx.x >> 6;
    const int l15  = lane & 15;
    const int quad = lane >> 4;

    int t = blockIdx.x * 4 + wv;
    const int nW = gridDim.x * 4;
    if (t >= nTiles) return;

    // B fragments: B[k][n], n=l15 (h), k=quad*8+j per 32-step. 24 longs = 48 VGPR.
    long B0[12], B1[12];
    {
        const unsigned char* b0p = w1T8 + (size_t)l15 * KTOT + quad * 8;
        const unsigned char* b1p = w1T8 + (size_t)(16 + l15) * KTOT + quad * 8;
#pragma unroll
        for (int s = 0; s < 12; s++) {
            B0[s] = *(const long*)(b0p + s * 32);
            B1[s] = *(const long*)(b1p + s * 32);
        }
    }
    const float b1a = b1[l15],      w2a = w2[l15];
    const float b1b = b1[16 + l15], w2b = w2[16 + l15];
    const float cbias = bias[0] + b2[0];

    for (; t < nTiles; t += nW) {
        const int e = t * TPW + l15;
        int s_ = 0, d_ = 0;
        if (e < nE) { s_ = ei[e]; d_ = ei[nE + e]; }
        const float bil = s1[s_] * s2[d_];         // f32 path, lane l15 = edge l15

        const unsigned char* zsp = zb8 + (size_t)s_ * DIM + quad * 8;
        const unsigned char* zdp = zb8 + (size_t)d_ * DIM + quad * 8;
        long zs[4], zd[4];
#pragma unroll
        for (int k = 0; k < 4; k++) {
            zs[k] = *(const long*)(zsp + k * 32);
            zd[k] = *(const long*)(zdp + k * 32);
        }

        f32x4 acc0 = {0.f, 0.f, 0.f, 0.f};
        f32x4 acc1 = {0.f, 0.f, 0.f, 0.f};
#pragma unroll
        for (int k = 0; k < 4; k++) {              // zs block (K 0..127)
            acc0 = __builtin_amdgcn_mfma_f32_16x16x32_fp8_fp8(zs[k], B0[k], acc0, 0, 0, 0);
            acc1 = __builtin_amdgcn_mfma_f32_16x16x32_fp8_fp8(zs[k], B1[k], acc1, 0, 0, 0);
        }
#pragma unroll
        for (int k = 0; k < 4; k++) {              // zd block (K 128..255)
            acc0 = __builtin_amdgcn_mfma_f32_16x16x32_fp8_fp8(zd[k], B0[4 + k], acc0, 0, 0, 0);
            acc1 = __builtin_amdgcn_mfma_f32_16x16x32_fp8_fp8(zd[k], B1[4 + k], acc1, 0, 0, 0);
        }
#pragma unroll
        for (int k = 0; k < 4; k++) {              // product block (K 256..383)
            long p = prod_fp8(zs[k], zd[k]);
            acc0 = __builtin_amdgcn_mfma_f32_16x16x32_fp8_fp8(p, B0[8 + k], acc0, 0, 0, 0);
            acc1 = __builtin_amdgcn_mfma_f32_16x16x32_fp8_fp8(p, B1[8 + k], acc1, 0, 0, 0);
        }

        // epilogue (validated R3/R5): C/D col=l15 (h), row=quad*4+r (edge)
        const int e0 = t * TPW;
#pragma unroll
        for (int r = 0; r < 4; r++) {
            float v = fmaxf(acc0[r] + b1a, 0.f) * w2a
                    + fmaxf(acc1[r] + b1b, 0.f) * w2b;
            v += __shfl_xor(v, 1); v += __shfl_xor(v, 2);
            v += __shfl_xor(v, 4); v += __shfl_xor(v, 8);
            const int eL = quad * 4 + r;
            const float bilr = __shfl(bil, eL);    // bil replicated across quads
            if (l15 == r && (e0 + eL) < nE)
                out[e0 + eL] = v + bilr + cbias;
        }
    }
}

// ---------------------------------------------------------------------------
// Workspace: zb8 uchar[nNodes*128] | s1 f32[nNodes] | s2 f32[nNodes]
//          | wsum f32[128] | w1T8 uchar[32*384]        (~13.7 MB)
// ---------------------------------------------------------------------------
extern "C" void kernel_launch(void* const* d_in, const int* in_sizes, int n_in,
                              void* d_out, int out_size, void* d_ws, size_t ws_size,
                              hipStream_t stream)
{
    const float* z    = (const float*)d_in[0];
    const int*   ei   = (const int*)d_in[1];
    const float* W    = (const float*)d_in[2];
    const float* bias = (const float*)d_in[3];
    const float* w1   = (const float*)d_in[4];
    const float* b1   = (const float*)d_in[5];
    const float* w2   = (const float*)d_in[6];
    const float* b2   = (const float*)d_in[7];
    float* out = (float*)d_out;

    const int nNodes = in_sizes[0] / DIM;
    const int nE = out_size;

    unsigned char* zb8 = (unsigned char*)d_ws;
    float* s1   = (float*)(zb8 + (size_t)nNodes * DIM);
    float* s2   = s1 + nNodes;
    float* wsum = s2 + nNodes;
    unsigned char* w1T8 = (unsigned char*)(wsum + DIM);

    wsum_kernel<<<1, 128, 0, stream>>>(W, wsum);

    const int nNodeBlk = (nNodes + 7) / 8;
    prep_kernel<<<nNodeBlk + 48, 256, 0, stream>>>(z, w1, wsum, zb8, w1T8,
                                                   s1, s2, nNodes, nNodeBlk);

    const int nTiles = (nE + TPW - 1) / TPW;
    int grid = 1024;
    if (grid * 4 > nTiles) grid = (nTiles + 3) / 4;
    edge_kernel<<<grid, 256, 0, stream>>>(zb8, ei, s1, s2, w1T8,
                                          b1, w2, b2, bias, out, nE, nTiles);
}